// Round 1
// 289.702 us; speedup vs baseline: 1.0068x; 1.0068x over previous
//
#include <hip/hip_runtime.h>
#include <hip/hip_bf16.h>

// GrahamLoss: B=16, C=128, HW=16384, fp32 in, fp32[16] out.
// K1: split-K bf16-MFMA partial grams -> ws. K2: float4 sum + diff^2 partial. K3: final.
//
// v2 changes vs 290us baseline:
//  - 128-col stages (512B/row contiguous, 64KB burst/block, 8 stages instead of 16)
//    -> half the vmcnt-drain sawtooths, 2x larger bursts.
//  - per-block stage-order rotation: decorrelates address bits [9:12) across the
//    GPU (previously all 512 blocks read the same 256B column-window in lockstep
//    at 64KB stride -> channel hot-spotting, effective ~2.4 TB/s during bursts).
//  - reduce1 rewritten: 256 blocks, float4 loads, fully unrolled S=16 path
//    (32 independent 16B loads in flight per thread instead of scalar waits).

typedef __attribute__((ext_vector_type(8))) short short8;
typedef __attribute__((ext_vector_type(4))) float f32x4;

#define CC 128
#define NN 16384

// fp32 -> bf16 round-to-nearest-even (bit math; inputs are finite)
__device__ __forceinline__ short f2bf(float x) {
    unsigned u = __builtin_bit_cast(unsigned, x);
    u += 0x7fffu + ((u >> 16) & 1u);
    return (short)(u >> 16);
}

__global__ __launch_bounds__(256, 2) void gram_partial_k(
    const float* __restrict__ f0, const float* __restrict__ f1,
    float* __restrict__ partials, int S, int Kc, int nst)
{
    // LDS: double buffer, 128 rows x 128 bf16, swizzled in 16B blocks: phys = cb ^ (r&15)
    __shared__ short lds[2][CC * 128];

    const int tid = threadIdx.x;
    const int bx  = blockIdx.x;
    const int g   = bx & 31;   // gram id: batch*2 + src
    const int s   = bx >> 5;   // k-chunk

    const float* src  = (g & 1) ? f1 : f0;
    const float* base = src + (size_t)(g >> 1) * ((size_t)CC * NN) + (size_t)s * Kc;

    // staging map: 16 threads per row (8 consecutive f32 each), 16 rows per sweep, 8 sweeps
    const int srow = tid >> 4;   // 0..15
    const int scb  = tid & 15;   // 16B-block index within 128-col stage
    const float* gp = base + (size_t)srow * NN + scb * 8;

    const int lane = tid & 63;
    const int w    = tid >> 6;
    const int m0   = (w & 1) * 64;
    const int n0   = (w >> 1) * 64;
    const int lr   = lane & 15;
    const int lk   = lane >> 4;

    // stage-order rotation phase (k-sum commutes; decorrelates column windows)
    const int rot = bx & (nst - 1);

    f32x4 acc[4][4];
    #pragma unroll
    for (int i = 0; i < 4; ++i)
        #pragma unroll
        for (int j = 0; j < 4; ++j)
            acc[i][j] = (f32x4){0.f, 0.f, 0.f, 0.f};

    float4 ra[8], rb[8];

    auto load_stage = [&](int st) {
        int sp = (st + rot) & (nst - 1);
        #pragma unroll
        for (int it = 0; it < 8; ++it) {
            const float* p = gp + (size_t)it * 16 * NN + (size_t)sp * 128;
            ra[it] = *(const float4*)p;
            rb[it] = *(const float4*)(p + 4);
        }
    };

    auto store_stage = [&](int buf) {
        #pragma unroll
        for (int it = 0; it < 8; ++it) {
            int r = srow + 16 * it;
            short8 v = { f2bf(ra[it].x), f2bf(ra[it].y), f2bf(ra[it].z), f2bf(ra[it].w),
                         f2bf(rb[it].x), f2bf(rb[it].y), f2bf(rb[it].z), f2bf(rb[it].w) };
            int phys = scb ^ (r & 15);
            *(short8*)&lds[buf][r * 128 + phys * 8] = v;
        }
    };

    auto compute = [&](int buf) {
        #pragma unroll
        for (int ks = 0; ks < 4; ++ks) {
            short8 af[4], bfr[4];
            int cb = ks * 4 + lk;
            #pragma unroll
            for (int i = 0; i < 4; ++i) {
                int r = m0 + i * 16 + lr;
                af[i] = *(const short8*)&lds[buf][r * 128 + ((cb ^ (r & 15)) * 8)];
            }
            #pragma unroll
            for (int i = 0; i < 4; ++i) {
                int r = n0 + i * 16 + lr;
                bfr[i] = *(const short8*)&lds[buf][r * 128 + ((cb ^ (r & 15)) * 8)];
            }
            #pragma unroll
            for (int mi = 0; mi < 4; ++mi)
                #pragma unroll
                for (int ni = 0; ni < 4; ++ni)
                    acc[mi][ni] = __builtin_amdgcn_mfma_f32_16x16x32_bf16(
                        af[mi], bfr[ni], acc[mi][ni], 0, 0, 0);
        }
    };

    load_stage(0);
    store_stage(0);
    __syncthreads();
    for (int st = 0; st < nst; ++st) {
        int cur = st & 1;
        bool more = (st + 1 < nst);
        if (more) load_stage(st + 1);
        compute(cur);
        if (more) store_stage(cur ^ 1);
        __syncthreads();
    }

    // epilogue: write partial gram (any consistent bijective lane->slot map is OK)
    float* op = partials + ((size_t)g * S + s) * (CC * CC);
    #pragma unroll
    for (int mi = 0; mi < 4; ++mi)
        #pragma unroll
        for (int ni = 0; ni < 4; ++ni)
            #pragma unroll
            for (int i = 0; i < 4; ++i) {
                int row = m0 + mi * 16 + lk * 4 + i;
                int col = n0 + ni * 16 + lr;
                op[row * CC + col] = acc[mi][ni][i];
            }
}

__global__ __launch_bounds__(256) void reduce1_k(
    const float* __restrict__ partials, float* __restrict__ part2, int S)
{
    int b     = blockIdx.x >> 4;   // batch
    int chunk = blockIdx.x & 15;   // 1024-entry chunk of the 16384-entry gram
    int t     = threadIdx.x;
    size_t e  = (size_t)chunk * 1024 + (size_t)t * 4;

    const f32x4* Pe = (const f32x4*)(partials + ((size_t)(2 * b) * S) * (CC * CC) + e);
    const f32x4* Pd = (const f32x4*)(partials + ((size_t)(2 * b + 1) * S) * (CC * CC) + e);
    const size_t stride = (size_t)CC * CC / 4;

    f32x4 ae = {0.f, 0.f, 0.f, 0.f}, ad = {0.f, 0.f, 0.f, 0.f};
    if (S == 16) {
        #pragma unroll
        for (int s2 = 0; s2 < 16; ++s2) {
            ae += Pe[(size_t)s2 * stride];
            ad += Pd[(size_t)s2 * stride];
        }
    } else {
        for (int s2 = 0; s2 < S; ++s2) {
            ae += Pe[(size_t)s2 * stride];
            ad += Pd[(size_t)s2 * stride];
        }
    }
    f32x4 d = ad - ae;
    float v = d[0] * d[0] + d[1] * d[1] + d[2] * d[2] + d[3] * d[3];
    #pragma unroll
    for (int off = 32; off > 0; off >>= 1) v += __shfl_down(v, off);
    __shared__ float wsum[4];
    if ((t & 63) == 0) wsum[t >> 6] = v;
    __syncthreads();
    if (t == 0) part2[b * 16 + chunk] = wsum[0] + wsum[1] + wsum[2] + wsum[3];
}

__global__ void reduce2_k(const float* __restrict__ part2, float* __restrict__ out)
{
    int b = blockIdx.x;
    int t = threadIdx.x;  // 64
    float v = (t < 16) ? part2[b * 16 + t] : 0.f;
    #pragma unroll
    for (int off = 8; off > 0; off >>= 1) v += __shfl_down(v, off);
    // denom = 4 * (HW)^2 * C^2 = 2^44 exactly
    if (t == 0) out[b] = v * (1.0f / 17592186044416.0f);
}

extern "C" void kernel_launch(void* const* d_in, const int* in_sizes, int n_in,
                              void* d_out, int out_size, void* d_ws, size_t ws_size,
                              hipStream_t stream)
{
    const float* f0 = (const float*)d_in[0];  // feat
    const float* f1 = (const float*)d_in[1];  // feat_decod
    float* out = (float*)d_out;

    // adaptive split-K: S power of 2 <= 16 such that partials fit in ws
    const size_t perS = 32ull * CC * CC * 4;  // 2 MiB per k-chunk unit (32 grams)
    const size_t tail = 16 * 16 * 4;
    int S = 16;
    while (S > 1 && perS * (size_t)S + tail > ws_size) S >>= 1;
    int Kc  = NN / S;
    int nst = Kc / 128;

    float* partials = (float*)d_ws;
    float* part2    = (float*)((char*)d_ws + perS * (size_t)S);

    gram_partial_k<<<32 * S, 256, 0, stream>>>(f0, f1, partials, S, Kc, nst);
    reduce1_k<<<16 * 16, 256, 0, stream>>>(partials, part2, S);
    reduce2_k<<<16, 64, 0, stream>>>(part2, out);
}